// Round 7
// baseline (468.001 us; speedup 1.0000x reference)
//
#include <hip/hip_runtime.h>

#define N_NODES 50000
#define N_EDGES 800000
#define NF 128   // node feature dim
#define EH 32    // edge hidden
#define NB 128   // dst buckets for CSR sort
#define BN 391   // nodes per bucket (128*391 = 50048 >= 50000)
#define NCH 256  // edge chunks
#define CE 3125  // edges per chunk (256*3125 = 800000 exactly)
#define NGB 12500  // gather blocks = N/4
#define NEB 6250   // edge blocks  = E/(32*4)

typedef __bf16 bf16x8 __attribute__((ext_vector_type(8)));
typedef float f32x4 __attribute__((ext_vector_type(4)));
typedef unsigned short u16x8 __attribute__((ext_vector_type(8)));
typedef unsigned short ushort_t;
typedef unsigned int uint_t;

__device__ inline ushort_t f2bf(float x) {
  uint_t u = __builtin_bit_cast(uint_t, x);
  return (ushort_t)((u + 0x7fffu + ((u >> 16) & 1u)) >> 16);
}
__device__ inline float blo(uint_t u) { return __builtin_bit_cast(float, u << 16); }
__device__ inline float bhi(uint_t u) { return __builtin_bit_cast(float, u & 0xffff0000u); }

// ---------------- prep: weight transpose+cast, input cast, chunk histogram ----------------
__global__ __launch_bounds__(256) void k_prepcast_hist(
    const float* __restrict__ ws1, const float* __restrict__ wn1,
    const float* __restrict__ ws2, const float* __restrict__ wn2,
    const float* __restrict__ ws3, const float* __restrict__ wn3,
    const float* __restrict__ wu1, const float* __restrict__ wv1,
    const float* __restrict__ wu2, const float* __restrict__ wv2,
    ushort_t* __restrict__ wt1, ushort_t* __restrict__ wt2, ushort_t* __restrict__ wt3,
    ushort_t* __restrict__ wp1, ushort_t* __restrict__ wp2,
    const float* __restrict__ x, ushort_t* __restrict__ xb,
    const int* __restrict__ edst, int* __restrict__ ghist) {
  __shared__ int h[NB];
  int blk = blockIdx.x;
  int t = threadIdx.x;
  if (blk < 448) {  // weight prep
    int i = blk * 256 + t;
    if (i < 98304) {
      int l = i >> 15;
      int j = i & 32767;
      int n = j >> 8, k = j & 255;
      const float* s = (l == 0) ? (k < 128 ? ws1 : wn1)
                     : (l == 1) ? (k < 128 ? ws2 : wn2)
                                : (k < 128 ? ws3 : wn3);
      float v = s[(k & 127) * 128 + n];
      ushort_t* d = (l == 0) ? wt1 : (l == 1) ? wt2 : wt3;
      d[n * 256 + k] = f2bf(v);
    } else if (i < 114688) {
      int j = i - 98304;
      int l = j >> 13;
      int m = j & 8191;
      int n = m >> 7, k = m & 127;
      const float* s = (l == 0) ? (n < 32 ? wu1 : wv1) : (n < 32 ? wu2 : wv2);
      float v = s[k * 32 + (n & 31)];
      ushort_t* d = (l == 0) ? wp1 : wp2;
      d[n * 128 + k] = f2bf(v);
    }
  } else if (blk < 6698) {  // input cast
    int i = (blk - 448) * 256 + t;
    float4 v = ((const float4*)x)[i];
    uint2 p;
    p.x = (uint_t)f2bf(v.x) | ((uint_t)f2bf(v.y) << 16);
    p.y = (uint_t)f2bf(v.z) | ((uint_t)f2bf(v.w) << 16);
    ((uint2*)xb)[i] = p;
  } else {  // per-chunk dst-bucket histogram
    int c = blk - 6698;
    if (t < NB) h[t] = 0;
    __syncthreads();
    int base = c * CE;
    for (int i = t; i < CE; i += 256) atomicAdd(&h[edst[base + i] / BN], 1);
    __syncthreads();
    if (t < NB) ghist[t * NCH + c] = h[t];  // bucket-major
  }
}

// f2: one-block exclusive scan of 128*256 = 32768 bucket-major counts
__global__ __launch_bounds__(1024) void f2_scan(int* __restrict__ g) {
  __shared__ int part[1024];
  int t = threadIdx.x;
  int base = t * 32;
  int loc[32];
  int s = 0;
  #pragma unroll
  for (int i = 0; i < 32; ++i) { loc[i] = g[base + i]; s += loc[i]; }
  part[t] = s;
  __syncthreads();
  for (int off = 1; off < 1024; off <<= 1) {
    int v = (t >= off) ? part[t - off] : 0;
    __syncthreads();
    part[t] += v;
    __syncthreads();
  }
  int run = part[t] - s;
  #pragma unroll
  for (int i = 0; i < 32; ++i) { int c = loc[i]; g[base + i] = run; run += c; }
}

// f3: bin packed (dst<<16|src) edges into bucket-major ebuf
__global__ __launch_bounds__(256) void f3_bin(const int* __restrict__ esrc,
                                              const int* __restrict__ edst,
                                              const int* __restrict__ gofs,
                                              uint_t* __restrict__ ebuf) {
  __shared__ int cur[NB];
  int t = threadIdx.x, c = blockIdx.x;
  if (t < NB) cur[t] = gofs[t * NCH + c];
  __syncthreads();
  int base = c * CE;
  for (int i = t; i < CE; i += 256) {
    int d = edst[base + i];
    int s = esrc[base + i];
    int p = atomicAdd(&cur[d / BN], 1);
    ebuf[p] = ((uint_t)d << 16) | (uint_t)s;
  }
}

// f4: per-bucket fine fill; also emits rowptr
__global__ __launch_bounds__(256) void f4_fill(const uint_t* __restrict__ ebuf,
                                               const int* __restrict__ gofs,
                                               int* __restrict__ rowptr,
                                               int* __restrict__ csr_src) {
  __shared__ int cnt[392];
  __shared__ int cur[392];
  int b = blockIdx.x, t = threadIdx.x;
  int bstart = gofs[b * NCH];
  int bend = (b == NB - 1) ? N_EDGES : gofs[(b + 1) * NCH];
  int nbase = b * BN;
  for (int i = t; i < 392; i += 256) cnt[i] = 0;
  __syncthreads();
  for (int i = bstart + t; i < bend; i += 256)
    atomicAdd(&cnt[(ebuf[i] >> 16) - nbase], 1);
  __syncthreads();
  if (t < 64) {  // wave-0 exclusive scan of cnt[0..390]
    int carry = 0;
    for (int base = 0; base < 392; base += 64) {
      int i = base + t;
      int v = (i < 391) ? cnt[i] : 0;
      int x = v;
      #pragma unroll
      for (int off = 1; off < 64; off <<= 1) {
        int y = __shfl_up(x, off, 64);
        if (t >= off) x += y;
      }
      if (i < 392) cur[i] = x - v + carry;
      carry += __shfl(x, 63, 64);
    }
  }
  __syncthreads();
  for (int i = t; i < BN; i += 256) {
    int g = nbase + i;
    if (g < N_NODES) rowptr[g] = bstart + cur[i];
  }
  if (b == NB - 1 && t == 0) rowptr[N_NODES] = N_EDGES;
  __syncthreads();
  for (int i = bstart + t; i < bend; i += 256) {
    uint_t pk = ebuf[i];
    int p = atomicAdd(&cur[(pk >> 16) - nbase], 1);
    csr_src[bstart + p] = (int)(pk & 0xffffu);
  }
}

// ---------------- fused: CSR mean-gather (blocks [0,ngb)) + edge MLP (rest) ----------------
// Gather: wave per node, half-wave per neighbor row, 16-wide unroll.
// Edge: 8 lanes per edge, 4 edges per group pipelined; sw2 transposed (bank-conflict-free).
template <int EFD>
__global__ __launch_bounds__(256) void k_edge_gather(
    // gather
    const ushort_t* __restrict__ hb, const int* __restrict__ rowptr,
    const int* __restrict__ csr_src, ushort_t* __restrict__ aggb, int ngb,
    // edge
    const ushort_t* __restrict__ hub, const ushort_t* __restrict__ hvb,
    const int* __restrict__ src, const int* __restrict__ dst,
    const float* __restrict__ ef, int ef_stride,
    const float* __restrict__ we, const float* __restrict__ b,
    const float* __restrict__ w2, const float* __restrict__ b2,
    float* __restrict__ out, int out_col,
    const float* __restrict__ copy_ef) {
  int tid = threadIdx.x;
  if ((int)blockIdx.x >= ngb) {
    // ======== edge-MLP path ========
    __shared__ float swe[EFD][EH];
    __shared__ float sw2t[4][EH];   // sw2t[j][c] = w2[c][j]
    __shared__ float sb[EH];
    __shared__ float sb2v[4];
    for (int i = tid; i < EFD * EH; i += 256) swe[i >> 5][i & 31] = we[i];
    if (tid < EH * 4) sw2t[tid & 3][tid >> 2] = w2[tid];
    if (tid < EH) sb[tid] = b[tid];
    if (tid < 4) sb2v[tid] = b2[tid];
    __syncthreads();
    int gi = (((int)blockIdx.x - ngb) * 256 + tid) >> 3;
    int q = tid & 7;
    int cb = q * 4;
    int e0 = gi * 4;
    uint2 au[4], av[4];
    float efv[4][EFD];
    #pragma unroll
    for (int r = 0; r < 4; ++r) {
      int e = e0 + r;
      int s = src[e], d = dst[e];
      au[r] = *(const uint2*)&hub[s * EH + cb];
      av[r] = *(const uint2*)&hvb[d * EH + cb];
      const float* efp = &ef[(long long)e * ef_stride];
      float4 v = *(const float4*)efp;
      efv[r][0] = v.x; efv[r][1] = v.y; efv[r][2] = v.z; efv[r][3] = v.w;
      if (EFD == 8) {
        float4 v1 = *(const float4*)(efp + 4);
        efv[r][4] = v1.x; efv[r][5] = v1.y; efv[r][6] = v1.z; efv[r][7] = v1.w;
      }
    }
    #pragma unroll
    for (int r = 0; r < 4; ++r) {
      int e = e0 + r;
      float t0 = blo(au[r].x) + blo(av[r].x) + sb[cb + 0];
      float t1 = bhi(au[r].x) + bhi(av[r].x) + sb[cb + 1];
      float t2 = blo(au[r].y) + blo(av[r].y) + sb[cb + 2];
      float t3 = bhi(au[r].y) + bhi(av[r].y) + sb[cb + 3];
      #pragma unroll
      for (int i = 0; i < EFD; ++i) {
        float efi = efv[r][i];
        t0 += efi * swe[i][cb + 0];
        t1 += efi * swe[i][cb + 1];
        t2 += efi * swe[i][cb + 2];
        t3 += efi * swe[i][cb + 3];
      }
      t0 = fmaxf(t0, 0.f); t1 = fmaxf(t1, 0.f);
      t2 = fmaxf(t2, 0.f); t3 = fmaxf(t3, 0.f);
      float o0 = t0 * sw2t[0][cb + 0] + t1 * sw2t[0][cb + 1] + t2 * sw2t[0][cb + 2] + t3 * sw2t[0][cb + 3];
      float o1 = t0 * sw2t[1][cb + 0] + t1 * sw2t[1][cb + 1] + t2 * sw2t[1][cb + 2] + t3 * sw2t[1][cb + 3];
      float o2 = t0 * sw2t[2][cb + 0] + t1 * sw2t[2][cb + 1] + t2 * sw2t[2][cb + 2] + t3 * sw2t[2][cb + 3];
      float o3 = t0 * sw2t[3][cb + 0] + t1 * sw2t[3][cb + 1] + t2 * sw2t[3][cb + 2] + t3 * sw2t[3][cb + 3];
      #pragma unroll
      for (int m = 4; m; m >>= 1) {
        o0 += __shfl_xor(o0, m, 64);
        o1 += __shfl_xor(o1, m, 64);
        o2 += __shfl_xor(o2, m, 64);
        o3 += __shfl_xor(o3, m, 64);
      }
      if (q == 0) {
        *(float4*)&out[(long long)e * 12 + out_col] =
            make_float4(o0 + sb2v[0], o1 + sb2v[1], o2 + sb2v[2], o3 + sb2v[3]);
      }
      if (copy_ef && q == 1) {
        *(float4*)&out[(long long)e * 12] = *(const float4*)&copy_ef[e * 4];
      }
    }
  } else {
    // ======== gather path ========
    int n = (int)blockIdx.x * 4 + (tid >> 6);
    if (n >= N_NODES) return;
    int lane = tid & 63;
    int half = lane >> 5;
    int l32 = lane & 31;
    int beg = rowptr[n], end = rowptr[n + 1];
    float f0 = 0.f, f1 = 0.f, f2 = 0.f, f3 = 0.f;
    int j = beg;
    for (; j + 16 <= end; j += 16) {
      #pragma unroll
      for (int u = 0; u < 8; u += 2) {
        int sa = csr_src[j + u * 2 + half];
        int sb_ = csr_src[j + u * 2 + 2 + half];
        uint2 ua = *(const uint2*)&hb[sa * NF + l32 * 4];
        uint2 ub_ = *(const uint2*)&hb[sb_ * NF + l32 * 4];
        f0 += blo(ua.x) + blo(ub_.x);
        f1 += bhi(ua.x) + bhi(ub_.x);
        f2 += blo(ua.y) + blo(ub_.y);
        f3 += bhi(ua.y) + bhi(ub_.y);
      }
    }
    for (; j + 2 <= end; j += 2) {
      int sa = csr_src[j + half];
      uint2 ua = *(const uint2*)&hb[sa * NF + l32 * 4];
      f0 += blo(ua.x); f1 += bhi(ua.x); f2 += blo(ua.y); f3 += bhi(ua.y);
    }
    if (j < end && half == 0) {
      int sa = csr_src[j];
      uint2 ua = *(const uint2*)&hb[sa * NF + l32 * 4];
      f0 += blo(ua.x); f1 += bhi(ua.x); f2 += blo(ua.y); f3 += bhi(ua.y);
    }
    f0 += __shfl_down(f0, 32, 64);
    f1 += __shfl_down(f1, 32, 64);
    f2 += __shfl_down(f2, 32, 64);
    f3 += __shfl_down(f3, 32, 64);
    if (half == 0) {
      int deg = end - beg;
      float inv = deg > 0 ? 1.0f / (float)deg : 0.f;
      uint2 p;
      p.x = (uint_t)f2bf(f0 * inv) | ((uint_t)f2bf(f1 * inv) << 16);
      p.y = (uint_t)f2bf(f2 * inv) | ((uint_t)f2bf(f3 * inv) << 16);
      *(uint2*)&aggb[n * NF + l32 * 4] = p;
    }
  }
}

// ---------------- SAGE MFMA + fused edge projections ----------------
__global__ __launch_bounds__(256) void k_sage_mfma(
    const ushort_t* __restrict__ xb, const ushort_t* __restrict__ ab,
    const ushort_t* __restrict__ wt,  // [128][256] bf16, k-contiguous
    const float* __restrict__ bias,
    ushort_t* __restrict__ out_bf, float* __restrict__ out_f32,
    const ushort_t* __restrict__ wp,  // [64][128] bf16 or nullptr
    ushort_t* __restrict__ hub, ushort_t* __restrict__ hvb,
    int M, int do_relu) {
  __shared__ ushort_t hs[64][136];
  int tid = threadIdx.x;
  int wave = tid >> 6, lane = tid & 63;
  int l16 = lane & 15, quad = lane >> 4;
  int row0 = blockIdx.x * 64;
  int n0 = wave * 32;
  f32x4 acc[4][2];
  #pragma unroll
  for (int a = 0; a < 4; ++a)
    #pragma unroll
    for (int b = 0; b < 2; ++b) acc[a][b] = (f32x4){0.f, 0.f, 0.f, 0.f};

  #pragma unroll
  for (int ks = 0; ks < 8; ++ks) {
    int k0 = ks * 32;
    const ushort_t* A = (ks < 4) ? xb : ab;
    int ka = (k0 & 127) + quad * 8;
    bf16x8 afr[4];
    #pragma unroll
    for (int mt = 0; mt < 4; ++mt) {
      int r = row0 + mt * 16 + l16;
      if (r >= M) r = M - 1;
      afr[mt] = __builtin_bit_cast(bf16x8, *(const u16x8*)&A[r * NF + ka]);
    }
    bf16x8 bfr[2];
    #pragma unroll
    for (int nt = 0; nt < 2; ++nt) {
      int n = n0 + nt * 16 + l16;
      bfr[nt] = __builtin_bit_cast(bf16x8, *(const u16x8*)&wt[n * 256 + k0 + quad * 8]);
    }
    #pragma unroll
    for (int mt = 0; mt < 4; ++mt)
      #pragma unroll
      for (int nt = 0; nt < 2; ++nt)
        acc[mt][nt] = __builtin_amdgcn_mfma_f32_16x16x32_bf16(
            afr[mt], bfr[nt], acc[mt][nt], 0, 0, 0);
  }

  #pragma unroll
  for (int nt = 0; nt < 2; ++nt) {
    int col = n0 + nt * 16 + l16;
    float bv = bias[col];
    #pragma unroll
    for (int mt = 0; mt < 4; ++mt) {
      #pragma unroll
      for (int reg = 0; reg < 4; ++reg) {
        int lr = mt * 16 + quad * 4 + reg;
        int r = row0 + lr;
        float v = acc[mt][nt][reg] + bv;
        if (do_relu) v = fmaxf(v, 0.f);
        if (r < M) {
          if (out_f32) out_f32[r * NF + col] = v;
          else         out_bf[r * NF + col] = f2bf(v);
        }
        if (wp) hs[lr][col] = f2bf(v);
      }
    }
  }

  if (wp) {
    __syncthreads();
    int nb2 = wave * 16;
    f32x4 pacc[4];
    #pragma unroll
    for (int a = 0; a < 4; ++a) pacc[a] = (f32x4){0.f, 0.f, 0.f, 0.f};
    #pragma unroll
    for (int ks = 0; ks < 4; ++ks) {
      int k0 = ks * 32;
      bf16x8 bfrp = __builtin_bit_cast(bf16x8,
          *(const u16x8*)&wp[(nb2 + l16) * NF + k0 + quad * 8]);
      #pragma unroll
      for (int mt = 0; mt < 4; ++mt) {
        bf16x8 afr = __builtin_bit_cast(bf16x8,
            *(const u16x8*)&hs[mt * 16 + l16][k0 + quad * 8]);
        pacc[mt] = __builtin_amdgcn_mfma_f32_16x16x32_bf16(afr, bfrp, pacc[mt], 0, 0, 0);
      }
    }
    int col = nb2 + l16;
    #pragma unroll
    for (int mt = 0; mt < 4; ++mt) {
      #pragma unroll
      for (int reg = 0; reg < 4; ++reg) {
        int r = row0 + mt * 16 + quad * 4 + reg;
        if (r < M) {
          ushort_t v = f2bf(pacc[mt][reg]);
          if (col < 32) hub[r * EH + col] = v;
          else          hvb[r * EH + col - 32] = v;
        }
      }
    }
  }
}

// ---------------- launch ----------------
extern "C" void kernel_launch(void* const* d_in, const int* in_sizes, int n_in,
                              void* d_out, int out_size, void* d_ws, size_t ws_size,
                              hipStream_t stream) {
  const float* inputs    = (const float*)d_in[0];
  const float* edge_feat = (const float*)d_in[1];
  const float* w_self1   = (const float*)d_in[2];
  const float* w_neigh1  = (const float*)d_in[3];
  const float* b_conv1   = (const float*)d_in[4];
  const float* eu1_wu    = (const float*)d_in[5];
  const float* eu1_wv    = (const float*)d_in[6];
  const float* eu1_we    = (const float*)d_in[7];
  const float* eu1_b     = (const float*)d_in[8];
  const float* eu1_w2    = (const float*)d_in[9];
  const float* eu1_b2    = (const float*)d_in[10];
  const float* w_self2   = (const float*)d_in[11];
  const float* w_neigh2  = (const float*)d_in[12];
  const float* b_conv2   = (const float*)d_in[13];
  const float* eu2_wu    = (const float*)d_in[14];
  const float* eu2_wv    = (const float*)d_in[15];
  const float* eu2_we    = (const float*)d_in[16];
  const float* eu2_b     = (const float*)d_in[17];
  const float* eu2_w2    = (const float*)d_in[18];
  const float* eu2_b2    = (const float*)d_in[19];
  const float* w_self3   = (const float*)d_in[20];
  const float* w_neigh3  = (const float*)d_in[21];
  const float* b_conv3   = (const float*)d_in[22];
  const int*   esrc      = (const int*)d_in[23];
  const int*   edst      = (const int*)d_in[24];

  float* out_h  = (float*)d_out;                           // [N,128]
  float* out_ef = (float*)d_out + (long long)N_NODES * NF; // [E,12]

  // workspace: int region then bf16 region
  int* iws     = (int*)d_ws;
  int* gofs    = iws;                 // 32768 (NB*NCH)
  uint_t* ebuf = (uint_t*)(iws + 32768);  // 800000
  int* rowptr  = iws + 832768;        // 50001 (pad 50016)
  int* csr_src = iws + 882784;        // 800000 -> ends 1682784
  ushort_t* ub = (ushort_t*)(iws + 1682784);  // byte off 6731136, %16==0
  ushort_t* xb   = ub;                        // N*128 = 6.4e6
  ushort_t* hAb  = ub + 6400000;
  ushort_t* hBb  = ub + 12800000;
  ushort_t* aggb = ub + 19200000;
  ushort_t* wt1  = ub + 25600000;             // 32768 each
  ushort_t* wt2  = ub + 25632768;
  ushort_t* wt3  = ub + 25665536;
  ushort_t* wp1  = ub + 25698304;             // 8192 each
  ushort_t* wp2  = ub + 25706496;
  // hu/hv layer1 alias hBb (not written until L2 sage); layer2 alias xb (dead after L1 sage)
  ushort_t* hub1 = hBb;
  ushort_t* hvb1 = hBb + (long long)N_NODES * EH;
  ushort_t* hub2 = xb;
  ushort_t* hvb2 = xb + (long long)N_NODES * EH;

  const int N = N_NODES;
  int gsage = (N + 63) / 64;  // 782

  // ---- prep (weights + cast + hist), CSR sort
  k_prepcast_hist<<<6954, 256, 0, stream>>>(
      w_self1, w_neigh1, w_self2, w_neigh2, w_self3, w_neigh3,
      eu1_wu, eu1_wv, eu2_wu, eu2_wv,
      wt1, wt2, wt3, wp1, wp2, inputs, xb, edst, gofs);
  f2_scan<<<1, 1024, 0, stream>>>(gofs);
  f3_bin<<<NCH, 256, 0, stream>>>(esrc, edst, gofs, ebuf);
  f4_fill<<<NB, 256, 0, stream>>>(ebuf, gofs, rowptr, csr_src);

  // ---- layer 1: gather (gather-only launch of the fused kernel)
  k_edge_gather<4><<<NGB, 256, 0, stream>>>(
      xb, rowptr, csr_src, aggb, NGB,
      hub1, hvb1, esrc, edst, edge_feat, 4, eu1_we, eu1_b, eu1_w2, eu1_b2,
      out_ef, 4, edge_feat);
  k_sage_mfma<<<gsage, 256, 0, stream>>>(xb, aggb, wt1, b_conv1, hAb, nullptr,
                                         wp1, hub1, hvb1, N, 1);
  // ---- fused: edge MLP layer1 + gather layer2
  k_edge_gather<4><<<NGB + NEB, 256, 0, stream>>>(
      hAb, rowptr, csr_src, aggb, NGB,
      hub1, hvb1, esrc, edst, edge_feat, 4, eu1_we, eu1_b, eu1_w2, eu1_b2,
      out_ef, 4, edge_feat);

  // ---- layer 2
  k_sage_mfma<<<gsage, 256, 0, stream>>>(hAb, aggb, wt2, b_conv2, hBb, nullptr,
                                         wp2, hub2, hvb2, N, 1);
  // ---- fused: edge MLP layer2 + gather layer3
  k_edge_gather<8><<<NGB + NEB, 256, 0, stream>>>(
      hBb, rowptr, csr_src, aggb, NGB,
      hub2, hvb2, esrc, edst, out_ef, 12, eu2_we, eu2_b, eu2_w2, eu2_b2,
      out_ef, 8, nullptr);

  // ---- layer 3 (no relu, fp32 output, no proj)
  k_sage_mfma<<<gsage, 256, 0, stream>>>(hBb, aggb, wt3, b_conv3, nullptr, out_h,
                                         nullptr, nullptr, nullptr, N, 0);
}